// Round 1
// baseline (74.470 us; speedup 1.0000x reference)
//
#include <hip/hip_runtime.h>

#define D 8192
#define T_STEPS 100
#define SPIKE_THR 0.5f
#define BLOCK 256
#define COLS_PER_THREAD 4
#define NCHUNK 64
#define ROWS_PER_CHUNK (D / NCHUNK)                    // 128
#define COLBLOCKS (D / (BLOCK * COLS_PER_THREAD))      // 8

// Kernel 1: partial column-dot-products over a row chunk + partial sum(|W|).
// grid = (COLBLOCKS, NCHUNK), block = BLOCK.
// ws_drive layout: [NCHUNK][D] floats. ws_abs: [NCHUNK*COLBLOCKS] floats.
__global__ void __launch_bounds__(BLOCK)
k_partial(const float* __restrict__ x, const float* __restrict__ W,
          float* __restrict__ ws_drive, float* __restrict__ ws_abs) {
    __shared__ float xs[ROWS_PER_CHUNK];
    __shared__ float red[BLOCK];

    const int chunk = blockIdx.y;
    const int row0  = chunk * ROWS_PER_CHUNK;
    for (int i = threadIdx.x; i < ROWS_PER_CHUNK; i += BLOCK)
        xs[i] = x[row0 + i];
    __syncthreads();

    const int j0 = (blockIdx.x * BLOCK + threadIdx.x) * COLS_PER_THREAD;

    float ax = 0.f, ay = 0.f, az = 0.f, aw = 0.f;
    float asum = 0.f;
    #pragma unroll 4
    for (int i = 0; i < ROWS_PER_CHUNK; ++i) {
        const float xv = xs[i];
        const float4 w = *reinterpret_cast<const float4*>(
            &W[(size_t)(row0 + i) * D + j0]);
        ax = fmaf(xv, w.x, ax);
        ay = fmaf(xv, w.y, ay);
        az = fmaf(xv, w.z, az);
        aw = fmaf(xv, w.w, aw);
        asum += fabsf(w.x) + fabsf(w.y) + fabsf(w.z) + fabsf(w.w);
    }

    float4 acc; acc.x = ax; acc.y = ay; acc.z = az; acc.w = aw;
    *reinterpret_cast<float4*>(&ws_drive[(size_t)chunk * D + j0]) = acc;

    // block-reduce |W| partial
    red[threadIdx.x] = asum;
    __syncthreads();
    for (int s = BLOCK / 2; s > 0; s >>= 1) {
        if (threadIdx.x < s) red[threadIdx.x] += red[threadIdx.x + s];
        __syncthreads();
    }
    if (threadIdx.x == 0)
        ws_abs[blockIdx.y * gridDim.x + blockIdx.x] = red[0];
}

// Kernel 2: reduce chunk partials -> drive[j]; run the 100-step sim in regs.
// grid = COLBLOCKS, block = BLOCK. out: spikes[T][D], potentials[T][D], act.
__global__ void __launch_bounds__(BLOCK)
k_sim(const float* __restrict__ ws_drive, const float* __restrict__ pot0,
      float* __restrict__ out) {
    const int j0 = (blockIdx.x * BLOCK + threadIdx.x) * COLS_PER_THREAD;

    float dx = 0.f, dy = 0.f, dz = 0.f, dw = 0.f;
    #pragma unroll 8
    for (int c = 0; c < NCHUNK; ++c) {
        const float4 p = *reinterpret_cast<const float4*>(
            &ws_drive[(size_t)c * D + j0]);
        dx += p.x; dy += p.y; dz += p.z; dw += p.w;
    }

    const float4 p0 = *reinterpret_cast<const float4*>(&pot0[j0]);
    float px = p0.x, py = p0.y, pz = p0.z, pw = p0.w;

    float* __restrict__ spikes = out;
    float* __restrict__ pots   = out + (size_t)T_STEPS * D;

    for (int t = 0; t < T_STEPS; ++t) {
        px += dx; py += dy; pz += dz; pw += dw;
        float4 sp;
        sp.x = (px >= SPIKE_THR) ? 1.f : 0.f;
        sp.y = (py >= SPIKE_THR) ? 1.f : 0.f;
        sp.z = (pz >= SPIKE_THR) ? 1.f : 0.f;
        sp.w = (pw >= SPIKE_THR) ? 1.f : 0.f;
        px *= (1.f - sp.x); py *= (1.f - sp.y);
        pz *= (1.f - sp.z); pw *= (1.f - sp.w);
        *reinterpret_cast<float4*>(&spikes[(size_t)t * D + j0]) = sp;
        float4 pv; pv.x = px; pv.y = py; pv.z = pz; pv.w = pw;
        *reinterpret_cast<float4*>(&pots[(size_t)t * D + j0]) = pv;
    }
}

// Kernel 3: reduce the NCHUNK*COLBLOCKS |W| partials -> mean into out[2*T*D].
__global__ void __launch_bounds__(BLOCK)
k_activity(const float* __restrict__ ws_abs, float* __restrict__ out) {
    __shared__ float red[BLOCK];
    const int n = NCHUNK * COLBLOCKS;  // 512
    float s = 0.f;
    for (int i = threadIdx.x; i < n; i += BLOCK) s += ws_abs[i];
    red[threadIdx.x] = s;
    __syncthreads();
    for (int st = BLOCK / 2; st > 0; st >>= 1) {
        if (threadIdx.x < st) red[threadIdx.x] += red[threadIdx.x + st];
        __syncthreads();
    }
    if (threadIdx.x == 0)
        out[(size_t)2 * T_STEPS * D] = red[0] / ((float)D * (float)D);
}

extern "C" void kernel_launch(void* const* d_in, const int* in_sizes, int n_in,
                              void* d_out, int out_size, void* d_ws, size_t ws_size,
                              hipStream_t stream) {
    const float* x   = (const float*)d_in[0];
    const float* W   = (const float*)d_in[1];
    const float* mp0 = (const float*)d_in[2];
    float* out = (float*)d_out;

    float* ws_drive = (float*)d_ws;                       // NCHUNK*D floats = 2 MiB
    float* ws_abs   = ws_drive + (size_t)NCHUNK * D;      // 512 floats

    dim3 g1(COLBLOCKS, NCHUNK);
    k_partial<<<g1, BLOCK, 0, stream>>>(x, W, ws_drive, ws_abs);
    k_sim<<<COLBLOCKS, BLOCK, 0, stream>>>(ws_drive, mp0, out);
    k_activity<<<1, BLOCK, 0, stream>>>(ws_abs, out);
}

// Round 2
// 67.576 us; speedup vs baseline: 1.1020x; 1.1020x over previous
//
#include <hip/hip_runtime.h>

#define D 8192
#define T_STEPS 100
#define SPIKE_THR 0.5f
#define BLOCK 256
#define COLS_PER_THREAD 4
#define NCHUNK 256
#define ROWS_PER_CHUNK (D / NCHUNK)                    // 32
#define COLBLOCKS (D / (BLOCK * COLS_PER_THREAD))      // 8

// Kernel 1: partial column-dot-products over a 32-row chunk + partial sum(|W|).
// grid = (COLBLOCKS, NCHUNK) = (8, 256) = 2048 blocks, block = 256.
// ws_drive: [NCHUNK][D] floats (8 MB). ws_abs: [NCHUNK*COLBLOCKS] floats.
__global__ void __launch_bounds__(BLOCK)
k_partial(const float* __restrict__ x, const float* __restrict__ W,
          float* __restrict__ ws_drive, float* __restrict__ ws_abs) {
    __shared__ float xs[ROWS_PER_CHUNK];
    __shared__ float red[BLOCK];

    const int chunk = blockIdx.y;
    const int row0  = chunk * ROWS_PER_CHUNK;
    if (threadIdx.x < ROWS_PER_CHUNK)
        xs[threadIdx.x] = x[row0 + threadIdx.x];
    __syncthreads();

    const int j0 = (blockIdx.x * BLOCK + threadIdx.x) * COLS_PER_THREAD;

    float ax = 0.f, ay = 0.f, az = 0.f, aw = 0.f;
    float asum = 0.f;
    #pragma unroll
    for (int i = 0; i < ROWS_PER_CHUNK; ++i) {
        const float xv = xs[i];
        const float4 w = *reinterpret_cast<const float4*>(
            &W[(size_t)(row0 + i) * D + j0]);
        ax = fmaf(xv, w.x, ax);
        ay = fmaf(xv, w.y, ay);
        az = fmaf(xv, w.z, az);
        aw = fmaf(xv, w.w, aw);
        asum += fabsf(w.x) + fabsf(w.y) + fabsf(w.z) + fabsf(w.w);
    }

    float4 acc; acc.x = ax; acc.y = ay; acc.z = az; acc.w = aw;
    *reinterpret_cast<float4*>(&ws_drive[(size_t)chunk * D + j0]) = acc;

    // block-reduce |W| partial
    red[threadIdx.x] = asum;
    __syncthreads();
    for (int s = BLOCK / 2; s > 0; s >>= 1) {
        if (threadIdx.x < s) red[threadIdx.x] += red[threadIdx.x + s];
        __syncthreads();
    }
    if (threadIdx.x == 0)
        ws_abs[blockIdx.y * gridDim.x + blockIdx.x] = red[0];
}

// Kernel 2: reduce chunk partials -> drive[j]; run the 100-step sim in regs.
// Block COLBLOCKS (the extra one) instead reduces ws_abs -> activity scalar.
// grid = COLBLOCKS + 1, block = BLOCK.
// out layout: spikes[T][D], potentials[T][D], activity (1).
__global__ void __launch_bounds__(BLOCK)
k_sim(const float* __restrict__ ws_drive, const float* __restrict__ ws_abs,
      const float* __restrict__ pot0, float* __restrict__ out) {
    if (blockIdx.x == COLBLOCKS) {
        // activity reduction over NCHUNK*COLBLOCKS = 2048 partials
        __shared__ float red[BLOCK];
        const int n = NCHUNK * COLBLOCKS;
        float s = 0.f;
        for (int i = threadIdx.x; i < n; i += BLOCK) s += ws_abs[i];
        red[threadIdx.x] = s;
        __syncthreads();
        for (int st = BLOCK / 2; st > 0; st >>= 1) {
            if (threadIdx.x < st) red[threadIdx.x] += red[threadIdx.x + st];
            __syncthreads();
        }
        if (threadIdx.x == 0)
            out[(size_t)2 * T_STEPS * D] = red[0] / ((float)D * (float)D);
        return;
    }

    const int j0 = (blockIdx.x * BLOCK + threadIdx.x) * COLS_PER_THREAD;

    float dx = 0.f, dy = 0.f, dz = 0.f, dw = 0.f;
    #pragma unroll 8
    for (int c = 0; c < NCHUNK; ++c) {
        const float4 p = *reinterpret_cast<const float4*>(
            &ws_drive[(size_t)c * D + j0]);
        dx += p.x; dy += p.y; dz += p.z; dw += p.w;
    }

    const float4 p0 = *reinterpret_cast<const float4*>(&pot0[j0]);
    float px = p0.x, py = p0.y, pz = p0.z, pw = p0.w;

    float* __restrict__ spikes = out;
    float* __restrict__ pots   = out + (size_t)T_STEPS * D;

    for (int t = 0; t < T_STEPS; ++t) {
        px += dx; py += dy; pz += dz; pw += dw;
        float4 sp;
        sp.x = (px >= SPIKE_THR) ? 1.f : 0.f;
        sp.y = (py >= SPIKE_THR) ? 1.f : 0.f;
        sp.z = (pz >= SPIKE_THR) ? 1.f : 0.f;
        sp.w = (pw >= SPIKE_THR) ? 1.f : 0.f;
        px *= (1.f - sp.x); py *= (1.f - sp.y);
        pz *= (1.f - sp.z); pw *= (1.f - sp.w);
        *reinterpret_cast<float4*>(&spikes[(size_t)t * D + j0]) = sp;
        float4 pv; pv.x = px; pv.y = py; pv.z = pz; pv.w = pw;
        *reinterpret_cast<float4*>(&pots[(size_t)t * D + j0]) = pv;
    }
}

extern "C" void kernel_launch(void* const* d_in, const int* in_sizes, int n_in,
                              void* d_out, int out_size, void* d_ws, size_t ws_size,
                              hipStream_t stream) {
    const float* x   = (const float*)d_in[0];
    const float* W   = (const float*)d_in[1];
    const float* mp0 = (const float*)d_in[2];
    float* out = (float*)d_out;

    float* ws_drive = (float*)d_ws;                       // NCHUNK*D floats = 8 MiB
    float* ws_abs   = ws_drive + (size_t)NCHUNK * D;      // 2048 floats

    dim3 g1(COLBLOCKS, NCHUNK);
    k_partial<<<g1, BLOCK, 0, stream>>>(x, W, ws_drive, ws_abs);
    k_sim<<<COLBLOCKS + 1, BLOCK, 0, stream>>>(ws_drive, ws_abs, mp0, out);
}

// Round 3
// 66.250 us; speedup vs baseline: 1.1241x; 1.0200x over previous
//
#include <hip/hip_runtime.h>

#define D 8192
#define T_STEPS 100
#define SPIKE_THR 0.5f
#define BLOCK 256
#define COLS_PER_THREAD 4
#define NCHUNK 256
#define ROWS_PER_CHUNK (D / NCHUNK)                    // 32
#define COLBLOCKS (D / (BLOCK * COLS_PER_THREAD))      // 8
#define STEPS_PER 4
#define TCHUNKS (T_STEPS / STEPS_PER)                  // 25

// Kernel 1: partial column-dot-products over a 32-row chunk + partial sum(|W|).
// grid = (COLBLOCKS, NCHUNK) = (8, 256) = 2048 blocks, block = 256.
// ws_drive: [NCHUNK][D] floats (8 MB). ws_abs: [NCHUNK*COLBLOCKS] floats.
__global__ void __launch_bounds__(BLOCK)
k_partial(const float* __restrict__ x, const float* __restrict__ W,
          float* __restrict__ ws_drive, float* __restrict__ ws_abs) {
    __shared__ float xs[ROWS_PER_CHUNK];
    __shared__ float red[BLOCK];

    const int chunk = blockIdx.y;
    const int row0  = chunk * ROWS_PER_CHUNK;
    if (threadIdx.x < ROWS_PER_CHUNK)
        xs[threadIdx.x] = x[row0 + threadIdx.x];
    __syncthreads();

    const int j0 = (blockIdx.x * BLOCK + threadIdx.x) * COLS_PER_THREAD;

    float ax = 0.f, ay = 0.f, az = 0.f, aw = 0.f;
    float asum = 0.f;
    #pragma unroll 8
    for (int i = 0; i < ROWS_PER_CHUNK; ++i) {
        const float xv = xs[i];
        const float4 w = *reinterpret_cast<const float4*>(
            &W[(size_t)(row0 + i) * D + j0]);
        ax = fmaf(xv, w.x, ax);
        ay = fmaf(xv, w.y, ay);
        az = fmaf(xv, w.z, az);
        aw = fmaf(xv, w.w, aw);
        asum += fabsf(w.x) + fabsf(w.y) + fabsf(w.z) + fabsf(w.w);
    }

    float4 acc; acc.x = ax; acc.y = ay; acc.z = az; acc.w = aw;
    *reinterpret_cast<float4*>(&ws_drive[(size_t)chunk * D + j0]) = acc;

    red[threadIdx.x] = asum;
    __syncthreads();
    for (int s = BLOCK / 2; s > 0; s >>= 1) {
        if (threadIdx.x < s) red[threadIdx.x] += red[threadIdx.x + s];
        __syncthreads();
    }
    if (threadIdx.x == 0)
        ws_abs[blockIdx.y * gridDim.x + blockIdx.x] = red[0];
}

// Kernel 2: reduce ws_drive[NCHUNK][D] -> drive[D]. grid = 33 blocks.
// Blocks 0..31: 256 cols each (1 col/thread, coalesced).
// Block 32: reduce ws_abs -> activity scalar at out[2*T*D].
__global__ void __launch_bounds__(BLOCK)
k_reduce(const float* __restrict__ ws_drive, const float* __restrict__ ws_abs,
         float* __restrict__ drive, float* __restrict__ out) {
    if (blockIdx.x == 32) {
        __shared__ float red[BLOCK];
        const int n = NCHUNK * COLBLOCKS;  // 2048
        float s = 0.f;
        for (int i = threadIdx.x; i < n; i += BLOCK) s += ws_abs[i];
        red[threadIdx.x] = s;
        __syncthreads();
        for (int st = BLOCK / 2; st > 0; st >>= 1) {
            if (threadIdx.x < st) red[threadIdx.x] += red[threadIdx.x + st];
            __syncthreads();
        }
        if (threadIdx.x == 0)
            out[(size_t)2 * T_STEPS * D] = red[0] / ((float)D * (float)D);
        return;
    }
    const int j = blockIdx.x * BLOCK + threadIdx.x;
    float s = 0.f;
    #pragma unroll 8
    for (int c = 0; c < NCHUNK; ++c)
        s += ws_drive[(size_t)c * D + j];
    drive[j] = s;
}

// Kernel 3: time-sliced sim. grid = (COLBLOCKS, TCHUNKS) = (8, 25) = 200 blocks.
// Each block warms up (no stores) to its chunk start, then stores STEPS_PER
// timesteps. out: spikes[T][D], potentials[T][D], activity.
__global__ void __launch_bounds__(BLOCK)
k_sim(const float* __restrict__ drive, const float* __restrict__ pot0,
      float* __restrict__ out) {
    const int j0 = (blockIdx.x * BLOCK + threadIdx.x) * COLS_PER_THREAD;
    const int t0 = blockIdx.y * STEPS_PER;

    const float4 d  = *reinterpret_cast<const float4*>(&drive[j0]);
    const float4 p0 = *reinterpret_cast<const float4*>(&pot0[j0]);
    float px = p0.x, py = p0.y, pz = p0.z, pw = p0.w;

    // warmup: simulate [0, t0) without stores
    for (int t = 0; t < t0; ++t) {
        px += d.x; py += d.y; pz += d.z; pw += d.w;
        px = (px >= SPIKE_THR) ? 0.f : px;
        py = (py >= SPIKE_THR) ? 0.f : py;
        pz = (pz >= SPIKE_THR) ? 0.f : pz;
        pw = (pw >= SPIKE_THR) ? 0.f : pw;
    }

    float* __restrict__ spikes = out;
    float* __restrict__ pots   = out + (size_t)T_STEPS * D;

    #pragma unroll
    for (int s = 0; s < STEPS_PER; ++s) {
        const int t = t0 + s;
        px += d.x; py += d.y; pz += d.z; pw += d.w;
        float4 sp;
        sp.x = (px >= SPIKE_THR) ? 1.f : 0.f;
        sp.y = (py >= SPIKE_THR) ? 1.f : 0.f;
        sp.z = (pz >= SPIKE_THR) ? 1.f : 0.f;
        sp.w = (pw >= SPIKE_THR) ? 1.f : 0.f;
        px *= (1.f - sp.x); py *= (1.f - sp.y);
        pz *= (1.f - sp.z); pw *= (1.f - sp.w);
        *reinterpret_cast<float4*>(&spikes[(size_t)t * D + j0]) = sp;
        float4 pv; pv.x = px; pv.y = py; pv.z = pz; pv.w = pw;
        *reinterpret_cast<float4*>(&pots[(size_t)t * D + j0]) = pv;
    }
}

extern "C" void kernel_launch(void* const* d_in, const int* in_sizes, int n_in,
                              void* d_out, int out_size, void* d_ws, size_t ws_size,
                              hipStream_t stream) {
    const float* x   = (const float*)d_in[0];
    const float* W   = (const float*)d_in[1];
    const float* mp0 = (const float*)d_in[2];
    float* out = (float*)d_out;

    float* ws_drive = (float*)d_ws;                       // NCHUNK*D floats = 8 MiB
    float* ws_abs   = ws_drive + (size_t)NCHUNK * D;      // 2048 floats
    float* drive    = ws_abs + NCHUNK * COLBLOCKS;        // D floats

    dim3 g1(COLBLOCKS, NCHUNK);
    k_partial<<<g1, BLOCK, 0, stream>>>(x, W, ws_drive, ws_abs);
    k_reduce<<<33, BLOCK, 0, stream>>>(ws_drive, ws_abs, drive, out);
    dim3 g3(COLBLOCKS, TCHUNKS);
    k_sim<<<g3, BLOCK, 0, stream>>>(drive, mp0, out);
}

// Round 4
// 58.562 us; speedup vs baseline: 1.2716x; 1.1313x over previous
//
#include <hip/hip_runtime.h>

#define D 8192
#define T_STEPS 100
#define SPIKE_THR 0.5f
#define BLOCK 256
#define COLS_PER_THREAD 4
#define NCHUNK 256
#define ROWS_PER_CHUNK (D / NCHUNK)                    // 32
#define COLBLOCKS (D / (BLOCK * COLS_PER_THREAD))      // 8
#define STEPS_PER 4
#define TCHUNKS (T_STEPS / STEPS_PER)                  // 25
#define RED_COLS 64                                    // cols per reduce block
#define RED_SEGS (BLOCK / RED_COLS)                    // 4 segments
#define RED_BLOCKS (D / RED_COLS)                      // 128

// Kernel 1: partial column-dot-products over a 32-row chunk + partial sum(|W|).
// grid = (COLBLOCKS, NCHUNK) = (8, 256) = 2048 blocks, block = 256.
__global__ void __launch_bounds__(BLOCK)
k_partial(const float* __restrict__ x, const float* __restrict__ W,
          float* __restrict__ ws_drive, float* __restrict__ ws_abs) {
    __shared__ float xs[ROWS_PER_CHUNK];
    __shared__ float red[BLOCK];

    const int chunk = blockIdx.y;
    const int row0  = chunk * ROWS_PER_CHUNK;
    if (threadIdx.x < ROWS_PER_CHUNK)
        xs[threadIdx.x] = x[row0 + threadIdx.x];
    __syncthreads();

    const int j0 = (blockIdx.x * BLOCK + threadIdx.x) * COLS_PER_THREAD;

    float ax = 0.f, ay = 0.f, az = 0.f, aw = 0.f;
    float asum = 0.f;
    #pragma unroll 8
    for (int i = 0; i < ROWS_PER_CHUNK; ++i) {
        const float xv = xs[i];
        const float4 w = *reinterpret_cast<const float4*>(
            &W[(size_t)(row0 + i) * D + j0]);
        ax = fmaf(xv, w.x, ax);
        ay = fmaf(xv, w.y, ay);
        az = fmaf(xv, w.z, az);
        aw = fmaf(xv, w.w, aw);
        asum += fabsf(w.x) + fabsf(w.y) + fabsf(w.z) + fabsf(w.w);
    }

    float4 acc; acc.x = ax; acc.y = ay; acc.z = az; acc.w = aw;
    *reinterpret_cast<float4*>(&ws_drive[(size_t)chunk * D + j0]) = acc;

    red[threadIdx.x] = asum;
    __syncthreads();
    for (int s = BLOCK / 2; s > 0; s >>= 1) {
        if (threadIdx.x < s) red[threadIdx.x] += red[threadIdx.x + s];
        __syncthreads();
    }
    if (threadIdx.x == 0)
        ws_abs[blockIdx.y * gridDim.x + blockIdx.x] = red[0];
}

// Kernel 2: reduce ws_drive[NCHUNK][D] -> drive[D].
// grid = RED_BLOCKS + 1 = 129. Blocks 0..127: 64 cols each; thread =
// (seg, col), each sums NCHUNK/RED_SEGS = 64 chunks for its column, wave
// loads are 64 consecutive floats (256 B). Block 128: ws_abs -> activity.
__global__ void __launch_bounds__(BLOCK)
k_reduce(const float* __restrict__ ws_drive, const float* __restrict__ ws_abs,
         float* __restrict__ drive, float* __restrict__ out) {
    if (blockIdx.x == RED_BLOCKS) {
        __shared__ float red[BLOCK];
        const int n = NCHUNK * COLBLOCKS;  // 2048
        float s = 0.f;
        for (int i = threadIdx.x; i < n; i += BLOCK) s += ws_abs[i];
        red[threadIdx.x] = s;
        __syncthreads();
        for (int st = BLOCK / 2; st > 0; st >>= 1) {
            if (threadIdx.x < st) red[threadIdx.x] += red[threadIdx.x + st];
            __syncthreads();
        }
        if (threadIdx.x == 0)
            out[(size_t)2 * T_STEPS * D] = red[0] / ((float)D * (float)D);
        return;
    }

    __shared__ float part[RED_SEGS][RED_COLS];
    const int col = threadIdx.x & (RED_COLS - 1);
    const int seg = threadIdx.x >> 6;                  // 0..3
    const int j   = blockIdx.x * RED_COLS + col;

    float s = 0.f;
    const int c0 = seg * (NCHUNK / RED_SEGS);          // 64 chunks per seg
    #pragma unroll 8
    for (int cc = 0; cc < NCHUNK / RED_SEGS; ++cc)
        s += ws_drive[(size_t)(c0 + cc) * D + j];
    part[seg][col] = s;
    __syncthreads();
    if (seg == 0)
        drive[j] = part[0][col] + part[1][col] + part[2][col] + part[3][col];
}

// Kernel 3: time-sliced sim. grid = (COLBLOCKS, TCHUNKS) = (8, 25) = 200 blocks.
__global__ void __launch_bounds__(BLOCK)
k_sim(const float* __restrict__ drive, const float* __restrict__ pot0,
      float* __restrict__ out) {
    const int j0 = (blockIdx.x * BLOCK + threadIdx.x) * COLS_PER_THREAD;
    const int t0 = blockIdx.y * STEPS_PER;

    const float4 d  = *reinterpret_cast<const float4*>(&drive[j0]);
    const float4 p0 = *reinterpret_cast<const float4*>(&pot0[j0]);
    float px = p0.x, py = p0.y, pz = p0.z, pw = p0.w;

    for (int t = 0; t < t0; ++t) {
        px += d.x; py += d.y; pz += d.z; pw += d.w;
        px = (px >= SPIKE_THR) ? 0.f : px;
        py = (py >= SPIKE_THR) ? 0.f : py;
        pz = (pz >= SPIKE_THR) ? 0.f : pz;
        pw = (pw >= SPIKE_THR) ? 0.f : pw;
    }

    float* __restrict__ spikes = out;
    float* __restrict__ pots   = out + (size_t)T_STEPS * D;

    #pragma unroll
    for (int s = 0; s < STEPS_PER; ++s) {
        const int t = t0 + s;
        px += d.x; py += d.y; pz += d.z; pw += d.w;
        float4 sp;
        sp.x = (px >= SPIKE_THR) ? 1.f : 0.f;
        sp.y = (py >= SPIKE_THR) ? 1.f : 0.f;
        sp.z = (pz >= SPIKE_THR) ? 1.f : 0.f;
        sp.w = (pw >= SPIKE_THR) ? 1.f : 0.f;
        px *= (1.f - sp.x); py *= (1.f - sp.y);
        pz *= (1.f - sp.z); pw *= (1.f - sp.w);
        *reinterpret_cast<float4*>(&spikes[(size_t)t * D + j0]) = sp;
        float4 pv; pv.x = px; pv.y = py; pv.z = pz; pv.w = pw;
        *reinterpret_cast<float4*>(&pots[(size_t)t * D + j0]) = pv;
    }
}

extern "C" void kernel_launch(void* const* d_in, const int* in_sizes, int n_in,
                              void* d_out, int out_size, void* d_ws, size_t ws_size,
                              hipStream_t stream) {
    const float* x   = (const float*)d_in[0];
    const float* W   = (const float*)d_in[1];
    const float* mp0 = (const float*)d_in[2];
    float* out = (float*)d_out;

    float* ws_drive = (float*)d_ws;                       // NCHUNK*D floats = 8 MiB
    float* ws_abs   = ws_drive + (size_t)NCHUNK * D;      // 2048 floats
    float* drive    = ws_abs + NCHUNK * COLBLOCKS;        // D floats

    dim3 g1(COLBLOCKS, NCHUNK);
    k_partial<<<g1, BLOCK, 0, stream>>>(x, W, ws_drive, ws_abs);
    k_reduce<<<RED_BLOCKS + 1, BLOCK, 0, stream>>>(ws_drive, ws_abs, drive, out);
    dim3 g3(COLBLOCKS, TCHUNKS);
    k_sim<<<g3, BLOCK, 0, stream>>>(drive, mp0, out);
}